// Round 5
// baseline (139.958 us; speedup 1.0000x reference)
//
#include <hip/hip_runtime.h>
#include <math.h>

// Problem constants (match reference)
#define NB   128   // batch
#define NN   16    // N agents
#define MM   32    // M other agents
#define DD   128   // obs dim = output dim = av dim
#define NACT 8
#define HH   64    // hidden
#define NTHR 1024  // 16 waves -> 4 waves/SIMD (was 2): latency hiding

// padded LDS strides (odd -> bank-bijective row access)
#define KT_P  17   // s_kT  [DD][KT_P]
#define KOT_P 33   // s_koT [DD][KOT_P]
#define W_P   17   // s_w   [NN][W_P]
#define WO_P  33   // s_wo  [NN][WO_P]
#define UV_P  65   // s_U/s_V [NN][UV_P]

__device__ __forceinline__ void fma4(float4& a, float s, const float4& w) {
    a.x += s * w.x; a.y += s * w.y; a.z += s * w.z; a.w += s * w.w;
}

// One workgroup per batch. Algebraic restructure (exact):
//   av[b,j,k,:] = (j==k) ? av_pol[b,k,:] : av_act[b,k,:]
//   wav[b,i,j,:] = base[b,i,:] + weight[b,i,j]*diff[b,j,:]
//   value[b,i,j] = sum_h lrelu(U[b,i,h] + weight[b,i,j]*V[b,j,h]) * W2[h]
__launch_bounds__(NTHR, 1)
__global__ void critic_fused(
    const float* __restrict__ states,     // [B,N,128]
    const float* __restrict__ policies,   // [B,N,8]
    const float* __restrict__ actions,    // [B,N,8]
    const float* __restrict__ states_o,   // [B,M,128]
    const float* __restrict__ actions_o,  // [B,M,8]
    const float* __restrict__ Wk,         // [128,128] (in,out)
    const float* __restrict__ Wq,
    const float* __restrict__ Wv,         // [136,128]
    const float* __restrict__ Wk_o,
    const float* __restrict__ Wq_o,
    const float* __restrict__ Wv_o,       // [136,128]
    const float* __restrict__ W1,         // [256,64]
    const float* __restrict__ W2,         // [64,1]
    float* __restrict__ out)              // value[B*256] | weight[B*256] | weight_o[B*512]
{
    __shared__ float s_st[NN][DD];
    __shared__ float s_pol[NN][NACT];
    __shared__ float s_act[NN][NACT];
    __shared__ float s_sto[MM][DD];
    __shared__ float s_acto[MM][NACT];
    __shared__ float s_q[NN][DD];
    __shared__ float s_qo[NN][DD];
    __shared__ float s_kT[DD][KT_P];    // k transposed, padded: score reads conflict-free
    __shared__ float s_koT[DD][KOT_P];  // k_o transposed, padded
    __shared__ float s_avact[NN][DD];
    __shared__ float s_avpol[NN][DD];
    __shared__ float s_avo[MM][DD];
    __shared__ float s_w[NN][W_P];      // weight (softmaxed), padded
    __shared__ float s_wo[NN][WO_P];    // weight_o (softmaxed), padded
    __shared__ float s_base[NN][DD];
    __shared__ float s_wavo[NN][DD];
    __shared__ float s_U[NN][UV_P];
    __shared__ float s_V[NN][UV_P];
    __shared__ float s_W2[HH];

    const int t = threadIdx.x;
    const int b = blockIdx.x;

    // ---------------- P0: load per-batch inputs (vectorized) ----------------
    {
        const float4* ps = (const float4*)(states + b * NN * DD);
        if (t < NN * DD / 4) ((float4*)&s_st[0][0])[t] = ps[t];
        const float4* po = (const float4*)(states_o + b * MM * DD);
        ((float4*)&s_sto[0][0])[t] = po[t];   // MM*DD/4 == 1024 == NTHR exactly
        if (t < NN * NACT) {
            (&s_pol[0][0])[t] = policies[b * NN * NACT + t];
            (&s_act[0][0])[t] = actions[b * NN * NACT + t];
        }
        if (t >= 128 && t < 128 + MM * NACT) (&s_acto[0][0])[t - 128] = actions_o[b * MM * NACT + (t - 128)];
        if (t >= 384 && t < 384 + HH) s_W2[t - 384] = W2[t - 384];
    }
    __syncthreads();

    // ---------------- P1: all projections, two wave-groups in parallel ----------------
    if (t < 512) {
        // state-side: thread = (row i, 4-col group). float4 weight loads.
        const int i = t >> 5;
        const int c4 = (t & 31) * 4;
        float4 aq = {0,0,0,0}, ak = {0,0,0,0}, aqo = {0,0,0,0}, av = {0,0,0,0};
        for (int kk = 0; kk < DD; ++kk) {
            float x = s_st[i][kk];
            float4 wq  = *(const float4*)(Wq   + kk * DD + c4);
            float4 wk  = *(const float4*)(Wk   + kk * DD + c4);
            float4 wqo = *(const float4*)(Wq_o + kk * DD + c4);
            float4 wv  = *(const float4*)(Wv   + kk * DD + c4);
            fma4(aq, x, wq); fma4(ak, x, wk); fma4(aqo, x, wqo); fma4(av, x, wv);
        }
        float4 aa = av, ap = av;
        for (int kk = 0; kk < NACT; ++kk) {
            float4 wv = *(const float4*)(Wv + (DD + kk) * DD + c4);
            fma4(aa, s_act[i][kk], wv);
            fma4(ap, s_pol[i][kk], wv);
        }
        *(float4*)&s_q[i][c4]  = aq;
        *(float4*)&s_qo[i][c4] = aqo;
        s_kT[c4 + 0][i] = ak.x; s_kT[c4 + 1][i] = ak.y;
        s_kT[c4 + 2][i] = ak.z; s_kT[c4 + 3][i] = ak.w;
        float4 taa; taa.x = tanhf(aa.x); taa.y = tanhf(aa.y); taa.z = tanhf(aa.z); taa.w = tanhf(aa.w);
        float4 tap; tap.x = tanhf(ap.x); tap.y = tanhf(ap.y); tap.z = tanhf(ap.z); tap.w = tanhf(ap.w);
        *(float4*)&s_avact[i][c4] = taa;
        *(float4*)&s_avpol[i][c4] = tap;
    } else {
        // other-side: thread = (rows r,r+16, 4-col group)
        const int tt = t - 512;
        const int r = tt >> 5;
        const int c4 = (tt & 31) * 4;
        float4 k0 = {0,0,0,0}, k1 = {0,0,0,0}, v0 = {0,0,0,0}, v1 = {0,0,0,0};
        for (int kk = 0; kk < DD; ++kk) {
            float x0 = s_sto[r][kk], x1 = s_sto[r + 16][kk];
            float4 wko = *(const float4*)(Wk_o + kk * DD + c4);
            float4 wvo = *(const float4*)(Wv_o + kk * DD + c4);
            fma4(k0, x0, wko); fma4(k1, x1, wko);
            fma4(v0, x0, wvo); fma4(v1, x1, wvo);
        }
        for (int kk = 0; kk < NACT; ++kk) {
            float4 wvo = *(const float4*)(Wv_o + (DD + kk) * DD + c4);
            fma4(v0, s_acto[r][kk], wvo);
            fma4(v1, s_acto[r + 16][kk], wvo);
        }
        s_koT[c4 + 0][r] = k0.x; s_koT[c4 + 1][r] = k0.y;
        s_koT[c4 + 2][r] = k0.z; s_koT[c4 + 3][r] = k0.w;
        s_koT[c4 + 0][r + 16] = k1.x; s_koT[c4 + 1][r + 16] = k1.y;
        s_koT[c4 + 2][r + 16] = k1.z; s_koT[c4 + 3][r + 16] = k1.w;
        float4 t0; t0.x = tanhf(v0.x); t0.y = tanhf(v0.y); t0.z = tanhf(v0.z); t0.w = tanhf(v0.w);
        float4 t1; t1.x = tanhf(v1.x); t1.y = tanhf(v1.y); t1.z = tanhf(v1.z); t1.w = tanhf(v1.w);
        *(float4*)&s_avo[r][c4]      = t0;
        *(float4*)&s_avo[r + 16][c4] = t1;
    }
    __syncthreads();

    // ---------------- P2: attention scores (conflict-free via transposed K) ----------------
    const float scale = 0.08838834764831845f;  // 1/sqrt(128)
    if (t < 512) {
        int i = t >> 5, m = t & 31;
        float acc = 0.f;
        for (int d = 0; d < DD; ++d) acc += s_qo[i][d] * s_koT[d][m];
        s_wo[i][m] = acc * scale;
    } else if (t < 768) {
        int tt = t - 512, i = tt >> 4, j = tt & 15;
        float acc = 0.f;
        for (int d = 0; d < DD; ++d) acc += s_q[i][d] * s_kT[d][j];
        s_w[i][j] = acc * scale;
    }
    __syncthreads();

    // ---------------- P3: softmaxes ----------------
    if (t < NN) {
        int i = t;  // softmax over j (key axis)
        float mx = -1e30f;
        #pragma unroll
        for (int j = 0; j < NN; ++j) mx = fmaxf(mx, s_w[i][j]);
        float e[NN], sum = 0.f;
        #pragma unroll
        for (int j = 0; j < NN; ++j) { e[j] = expf(s_w[i][j] - mx); sum += e[j]; }
        float inv = 1.f / sum;
        #pragma unroll
        for (int j = 0; j < NN; ++j) s_w[i][j] = e[j] * inv;
    } else if (t >= 64 && t < 64 + MM) {
        int m = t - 64;  // softmax over agent axis i (dim=1)
        float mx = -1e30f;
        #pragma unroll
        for (int i = 0; i < NN; ++i) mx = fmaxf(mx, s_wo[i][m]);
        float e[NN], sum = 0.f;
        #pragma unroll
        for (int i = 0; i < NN; ++i) { e[i] = expf(s_wo[i][m] - mx); sum += e[i]; }
        float inv = 1.f / sum;
        #pragma unroll
        for (int i = 0; i < NN; ++i) s_wo[i][m] = e[i] * inv;
    }
    __syncthreads();

    // ---------------- P4: write weight outputs; base = w@av_act, wav_o = w_o@av_o ----------------
    {
        float* ow = out + NB * NN * NN;       // ret_weight [B,N,N]
        if (t < NN * NN) ow[b * NN * NN + t] = s_w[t >> 4][t & 15];
        float* owo = out + 2 * NB * NN * NN;  // weight_o [B,N,M,1]
        if (t >= 256 && t < 256 + NN * MM) {
            int idx = t - 256;
            owo[b * NN * MM + idx] = s_wo[idx >> 5][idx & 31];
        }
    }
    {
        int i0 = t >> 7;       // 0..7 -> rows i0, i0+8 (wave-uniform: broadcast reads)
        int c  = t & 127;
        float b0 = 0.f, b1 = 0.f, w0 = 0.f, w1 = 0.f;
        #pragma unroll
        for (int kk = 0; kk < NN; ++kk) {
            float a = s_avact[kk][c];
            b0 += s_w[i0][kk] * a;
            b1 += s_w[i0 + 8][kk] * a;
        }
        #pragma unroll
        for (int m = 0; m < MM; ++m) {
            float a = s_avo[m][c];
            w0 += s_wo[i0][m] * a;
            w1 += s_wo[i0 + 8][m] * a;
        }
        s_base[i0][c] = b0; s_base[i0 + 8][c] = b1;
        s_wavo[i0][c] = w0; s_wavo[i0 + 8][c] = w1;
    }
    __syncthreads();

    // ---------------- P5: U = base@W1a + wav_o@W1b, V = diff@W1a ----------------
    {
        int i = t >> 6;   // 0..15 (wave-uniform)
        int h = t & 63;
        float u = 0.f, v = 0.f;
        for (int d = 0; d < DD; ++d) {
            float w1a = W1[d * HH + h];
            float w1b = W1[(DD + d) * HH + h];
            float bs = s_base[i][d];
            float wv = s_wavo[i][d];
            float df = s_avpol[i][d] - s_avact[i][d];
            u += bs * w1a + wv * w1b;
            v += df * w1a;
        }
        s_U[i][h] = u;
        s_V[i][h] = v;
    }
    __syncthreads();

    // ---------------- P6: value[i,j] = sum_h lrelu(U[i,h] + w[i,j]*V[j,h]) * W2[h] ----------------
    if (t < NN * NN) {
        int i = t >> 4, j = t & 15;
        float wij = s_w[i][j];
        float acc = 0.f;
        #pragma unroll
        for (int h = 0; h < HH; ++h) {
            float x = s_U[i][h] + wij * s_V[j][h];
            x = (x > 0.f) ? x : 0.01f * x;  // leaky_relu, slope 0.01
            acc += x * s_W2[h];
        }
        out[b * NN * NN + t] = acc;
    }
}

extern "C" void kernel_launch(void* const* d_in, const int* in_sizes, int n_in,
                              void* d_out, int out_size, void* d_ws, size_t ws_size,
                              hipStream_t stream) {
    const float* states    = (const float*)d_in[0];
    const float* policies  = (const float*)d_in[1];
    const float* actions   = (const float*)d_in[2];
    const float* states_o  = (const float*)d_in[3];
    const float* actions_o = (const float*)d_in[4];
    const float* Wk        = (const float*)d_in[5];
    const float* Wq        = (const float*)d_in[6];
    const float* Wv        = (const float*)d_in[7];
    const float* Wk_o      = (const float*)d_in[8];
    const float* Wq_o      = (const float*)d_in[9];
    const float* Wv_o      = (const float*)d_in[10];
    const float* W1        = (const float*)d_in[11];
    const float* W2        = (const float*)d_in[12];
    float* out = (float*)d_out;

    hipLaunchKernelGGL(critic_fused, dim3(NB), dim3(NTHR), 0, stream,
                       states, policies, actions, states_o, actions_o,
                       Wk, Wq, Wv, Wk_o, Wq_o, Wv_o, W1, W2, out);
}

// Round 6
// 117.959 us; speedup vs baseline: 1.1865x; 1.1865x over previous
//
#include <hip/hip_runtime.h>
#include <math.h>

// Problem constants
#define NB   128
#define NN   16
#define MM   32
#define DD   128
#define NACT 8
#define HH   64

// Static device scratch (floats). Fully rewritten every call.
#define OFF_G   0                       // [128,128] Gram: Wq @ Wk^T
#define OFF_GO  16384                   // [128,128] Gram: Wq_o @ Wk_o^T
#define OFF_Q   32768                   // q'  = st @ G   [B,16,128]
#define OFF_QO  (OFF_Q  + NB*NN*DD)     // q'o = st @ Go  [B,16,128]
#define OFF_P   (OFF_QO + NB*NN*DD)     // P  = avact @ W1a [B,16,64]
#define OFF_PO  (OFF_P  + NB*NN*HH)     // Po = avo   @ W1b [B,32,64]
#define OFF_V   (OFF_PO + NB*MM*HH)     // V  = (avpol-avact) @ W1a [B,16,64]
#define WS_FLOATS (OFF_V + NB*NN*HH)    // = 1,081,344 floats (~4.33 MB)

__device__ float g_ws[WS_FLOATS];

// ---------------- k0: Gram matrices G = Wq @ Wk^T, Go = Wq_o @ Wk_o^T ----------------
// grid 128: blocks 0..63 -> G tiles (8x8 of 16x16), 64..127 -> Go tiles.
__launch_bounds__(256)
__global__ void k0_gram(const float* __restrict__ Wq,  const float* __restrict__ Wk,
                        const float* __restrict__ Wqo, const float* __restrict__ Wko) {
    __shared__ float sA[16 * 129];
    __shared__ float sB[16 * 129];
    const int blk = blockIdx.x;
    const int mat = blk >> 6;
    const int tile = blk & 63;
    const int r0 = (tile >> 3) * 16, c0 = (tile & 7) * 16;
    const float* A  = mat ? Wqo : Wq;
    const float* Bm = mat ? Wko : Wk;
    float* outp = g_ws + (mat ? OFF_GO : OFF_G);
    const int t = threadIdx.x;
    for (int idx = t; idx < 16 * 128; idx += 256) {
        int r = idx >> 7, c = idx & 127;
        sA[r * 129 + c] = A [(r0 + r) * 128 + c];
        sB[r * 129 + c] = Bm[(c0 + r) * 128 + c];
    }
    __syncthreads();
    const int r = t >> 4, c = t & 15;
    float acc = 0.f;
    #pragma unroll 8
    for (int o = 0; o < 128; ++o) acc += sA[r * 129 + o] * sB[c * 129 + o];
    outp[(r0 + r) * 128 + (c0 + c)] = acc;
}

// ---------------- k1: per-batch projections + W1 pre-application ----------------
// grid 256 = batch*2. side0: q'=st@G, q'o=st@Go, avact/avpol=tanh(..@Wv), P=avact@W1a,
// V=(avpol-avact)@W1a.  side1: avo=tanh(oao@Wv_o), Po=avo@W1b.
#define AVO_P 132
__launch_bounds__(512)
__global__ void k1_proj(const float* __restrict__ states,   const float* __restrict__ policies,
                        const float* __restrict__ actions,  const float* __restrict__ states_o,
                        const float* __restrict__ actions_o,
                        const float* __restrict__ Wv, const float* __restrict__ Wvo,
                        const float* __restrict__ W1) {
    __shared__ float sm[4096 + 256 + 32 * AVO_P];   // side1 is the max (8576 floats)
    const int bs = blockIdx.x >> 1;
    const int side = blockIdx.x & 1;
    const int t = threadIdx.x;

    if (side == 0) {
        float* s_st = sm;          // [16][128]
        float* s_ac = sm + 2048;   // [16][8]
        float* s_po = sm + 2176;   // [16][8]
        float* s_aa = sm + 2304;   // avact [16][128]
        float* s_ap = sm + 4352;   // avpol [16][128]
        ((float4*)s_st)[t] = ((const float4*)(states + bs * NN * DD))[t];  // 512 f4 = 2048
        if (t < NN * NACT) {
            s_ac[t] = actions [bs * NN * NACT + t];
            s_po[t] = policies[bs * NN * NACT + t];
        }
        __syncthreads();
        {
            const int g = t >> 7, c = t & 127;   // rows g,g+4,g+8,g+12 ; col c
            float q4[4] = {0,0,0,0}, qo4[4] = {0,0,0,0}, av4[4] = {0,0,0,0};
            const float* G  = g_ws + OFF_G;
            const float* Go = g_ws + OFF_GO;
            for (int kk = 0; kk < DD; ++kk) {
                float wg = G[kk * 128 + c], wgo = Go[kk * 128 + c], wv = Wv[kk * 128 + c];
                #pragma unroll
                for (int u = 0; u < 4; ++u) {
                    float x = s_st[(g + 4 * u) * 128 + kk];
                    q4[u] += x * wg; qo4[u] += x * wgo; av4[u] += x * wv;
                }
            }
            float aa[4], ap[4];
            #pragma unroll
            for (int u = 0; u < 4; ++u) { aa[u] = av4[u]; ap[u] = av4[u]; }
            for (int kk = 0; kk < NACT; ++kk) {
                float wv = Wv[(DD + kk) * 128 + c];
                #pragma unroll
                for (int u = 0; u < 4; ++u) {
                    aa[u] += s_ac[(g + 4 * u) * NACT + kk] * wv;
                    ap[u] += s_po[(g + 4 * u) * NACT + kk] * wv;
                }
            }
            #pragma unroll
            for (int u = 0; u < 4; ++u) {
                int row = g + 4 * u;
                g_ws[OFF_Q  + bs * 2048 + row * 128 + c] = q4[u];
                g_ws[OFF_QO + bs * 2048 + row * 128 + c] = qo4[u];
                s_aa[row * 128 + c] = tanhf(aa[u]);
                s_ap[row * 128 + c] = tanhf(ap[u]);
            }
        }
        __syncthreads();
        {
            const int i = t >> 5, h2 = (t & 31) * 2;
            float p0 = 0.f, p1 = 0.f, v0 = 0.f, v1 = 0.f;
            for (int kk = 0; kk < DD; ++kk) {
                float2 w = *(const float2*)(W1 + kk * HH + h2);   // W1a row kk
                float a = s_aa[i * 128 + kk];
                float d = s_ap[i * 128 + kk] - a;
                p0 += a * w.x; p1 += a * w.y;
                v0 += d * w.x; v1 += d * w.y;
            }
            *(float2*)(g_ws + OFF_P + bs * NN * HH + i * HH + h2) = make_float2(p0, p1);
            *(float2*)(g_ws + OFF_V + bs * NN * HH + i * HH + h2) = make_float2(v0, v1);
        }
    } else {
        float* s_so = sm;          // [32][128]
        float* s_ao = sm + 4096;   // [32][8]
        float* s_av = sm + 4352;   // avo [32][AVO_P] padded
        ((float4*)s_so)[t]       = ((const float4*)(states_o + bs * MM * DD))[t];
        ((float4*)s_so)[t + 512] = ((const float4*)(states_o + bs * MM * DD))[t + 512];
        if (t < MM * NACT) s_ao[t] = actions_o[bs * MM * NACT + t];
        __syncthreads();
        {
            const int g = t >> 7, c = t & 127;   // rows g,g+4,...,g+28 (8 rows)
            float av8[8] = {0,0,0,0,0,0,0,0};
            for (int kk = 0; kk < DD; ++kk) {
                float wvo = Wvo[kk * 128 + c];
                #pragma unroll
                for (int u = 0; u < 8; ++u) av8[u] += s_so[(g + 4 * u) * 128 + kk] * wvo;
            }
            for (int kk = 0; kk < NACT; ++kk) {
                float wvo = Wvo[(DD + kk) * 128 + c];
                #pragma unroll
                for (int u = 0; u < 8; ++u) av8[u] += s_ao[(g + 4 * u) * NACT + kk] * wvo;
            }
            #pragma unroll
            for (int u = 0; u < 8; ++u) s_av[(g + 4 * u) * AVO_P + c] = tanhf(av8[u]);
        }
        __syncthreads();
        {
            const int r = t >> 4, h4 = (t & 15) * 4;
            float4 acc = {0.f, 0.f, 0.f, 0.f};
            for (int kk = 0; kk < DD; ++kk) {
                float4 w = *(const float4*)(W1 + (DD + kk) * HH + h4);   // W1b row kk
                float a = s_av[r * AVO_P + kk];
                acc.x += a * w.x; acc.y += a * w.y; acc.z += a * w.z; acc.w += a * w.w;
            }
            *(float4*)(g_ws + OFF_PO + bs * MM * HH + r * HH + h4) = acc;
        }
    }
}

// ---------------- k2: scores, softmaxes, U = w@P + wo@Po, value ----------------
__launch_bounds__(512)
__global__ void k2_attn(const float* __restrict__ states, const float* __restrict__ states_o,
                        const float* __restrict__ W2, float* __restrict__ out) {
    __shared__ float s_q [16 * 129];
    __shared__ float s_qo[16 * 129];
    __shared__ float s_st[16 * 129];
    __shared__ float s_so[32 * 129];
    __shared__ float s_P [16 * 64];
    __shared__ float s_Po[32 * 64];
    __shared__ float s_V [16 * 65];
    __shared__ float s_U [16 * 65];
    __shared__ float s_w [16 * 17];
    __shared__ float s_wo[16 * 33];
    __shared__ float s_W2[64];
    const int b = blockIdx.x, t = threadIdx.x;

    for (int idx = t; idx < NN * DD; idx += 512) {
        int r = idx >> 7, d = idx & 127;
        s_q [r * 129 + d] = g_ws[OFF_Q  + b * 2048 + idx];
        s_qo[r * 129 + d] = g_ws[OFF_QO + b * 2048 + idx];
        s_st[r * 129 + d] = states[b * 2048 + idx];
    }
    for (int idx = t; idx < MM * DD; idx += 512) {
        int r = idx >> 7, d = idx & 127;
        s_so[r * 129 + d] = states_o[b * 4096 + idx];
    }
    if (t < 256) ((float4*)s_P)[t] = ((const float4*)(g_ws + OFF_P + b * NN * HH))[t];
    ((float4*)s_Po)[t] = ((const float4*)(g_ws + OFF_PO + b * MM * HH))[t];   // 512 f4
    for (int idx = t; idx < NN * HH; idx += 512) {
        int r = idx >> 6, h = idx & 63;
        s_V[r * 65 + h] = g_ws[OFF_V + b * NN * HH + idx];
    }
    if (t < HH) s_W2[t] = W2[t];
    __syncthreads();

    const float scale = 0.08838834764831845f;   // 1/sqrt(128)
    {   // score_o[i,m] = q'o[i] . st_o[m]
        int i = t >> 5, m = t & 31;
        float acc = 0.f;
        #pragma unroll 8
        for (int d = 0; d < DD; ++d) acc += s_qo[i * 129 + d] * s_so[m * 129 + d];
        s_wo[i * 33 + m] = acc * scale;
    }
    if (t < 256) {   // score[i,j] = q'[i] . st[j]
        int i = t >> 4, j = t & 15;
        float acc = 0.f;
        #pragma unroll 8
        for (int d = 0; d < DD; ++d) acc += s_q[i * 129 + d] * s_st[j * 129 + d];
        s_w[i * 17 + j] = acc * scale;
    }
    __syncthreads();

    if (t < NN) {        // softmax over key axis j
        int i = t;
        float mx = -1e30f;
        #pragma unroll
        for (int j = 0; j < NN; ++j) mx = fmaxf(mx, s_w[i * 17 + j]);
        float e[NN], sum = 0.f;
        #pragma unroll
        for (int j = 0; j < NN; ++j) { e[j] = expf(s_w[i * 17 + j] - mx); sum += e[j]; }
        float inv = 1.f / sum;
        #pragma unroll
        for (int j = 0; j < NN; ++j) s_w[i * 17 + j] = e[j] * inv;
    } else if (t >= 64 && t < 64 + MM) {   // softmax over agent axis i (dim=1)
        int m = t - 64;
        float mx = -1e30f;
        #pragma unroll
        for (int i = 0; i < NN; ++i) mx = fmaxf(mx, s_wo[i * 33 + m]);
        float e[NN], sum = 0.f;
        #pragma unroll
        for (int i = 0; i < NN; ++i) { e[i] = expf(s_wo[i * 33 + m] - mx); sum += e[i]; }
        float inv = 1.f / sum;
        #pragma unroll
        for (int i = 0; i < NN; ++i) s_wo[i * 33 + m] = e[i] * inv;
    }
    __syncthreads();

    // weight outputs
    if (t < NN * NN) out[NB * 256 + b * 256 + t] = s_w[(t >> 4) * 17 + (t & 15)];
    out[2 * NB * 256 + b * 512 + t] = s_wo[(t >> 5) * 33 + (t & 31)];

    {   // U[i,h] = sum_k w[i,k] P[k,h] + sum_m wo[i,m] Po[m,h]
        int i = t >> 5, h2 = (t & 31) * 2;
        float u0 = 0.f, u1 = 0.f;
        #pragma unroll
        for (int k = 0; k < NN; ++k) {
            float w = s_w[i * 17 + k];
            u0 += w * s_P[k * 64 + h2];
            u1 += w * s_P[k * 64 + h2 + 1];
        }
        #pragma unroll
        for (int m = 0; m < MM; ++m) {
            float w = s_wo[i * 33 + m];
            u0 += w * s_Po[m * 64 + h2];
            u1 += w * s_Po[m * 64 + h2 + 1];
        }
        s_U[i * 65 + h2]     = u0;
        s_U[i * 65 + h2 + 1] = u1;
    }
    __syncthreads();

    if (t < NN * NN) {   // value[i,j] = sum_h lrelu(U[i,h] + w[i,j] V[j,h]) W2[h]
        int i = t >> 4, j = t & 15;
        float wij = s_w[i * 17 + j];
        float acc = 0.f;
        #pragma unroll
        for (int h = 0; h < HH; ++h) {
            float x = s_U[i * 65 + h] + wij * s_V[j * 65 + h];
            x = (x > 0.f) ? x : 0.01f * x;
            acc += x * s_W2[h];
        }
        out[b * 256 + t] = acc;
    }
}

extern "C" void kernel_launch(void* const* d_in, const int* in_sizes, int n_in,
                              void* d_out, int out_size, void* d_ws, size_t ws_size,
                              hipStream_t stream) {
    const float* states    = (const float*)d_in[0];
    const float* policies  = (const float*)d_in[1];
    const float* actions   = (const float*)d_in[2];
    const float* states_o  = (const float*)d_in[3];
    const float* actions_o = (const float*)d_in[4];
    const float* Wk        = (const float*)d_in[5];
    const float* Wq        = (const float*)d_in[6];
    const float* Wv        = (const float*)d_in[7];
    const float* Wk_o      = (const float*)d_in[8];
    const float* Wq_o      = (const float*)d_in[9];
    const float* Wv_o      = (const float*)d_in[10];
    const float* W1        = (const float*)d_in[11];
    const float* W2        = (const float*)d_in[12];
    float* out = (float*)d_out;

    hipLaunchKernelGGL(k0_gram, dim3(128), dim3(256), 0, stream, Wq, Wk, Wq_o, Wk_o);
    hipLaunchKernelGGL(k1_proj, dim3(256), dim3(512), 0, stream,
                       states, policies, actions, states_o, actions_o, Wv, Wv_o, W1);
    hipLaunchKernelGGL(k2_attn, dim3(128), dim3(512), 0, stream, states, states_o, W2, out);
}